// Round 10
// baseline (218.621 us; speedup 1.0000x reference)
//
#include <hip/hip_runtime.h>
#include <hip/hip_bf16.h>

// out[b,o,n] = sum_{k<19,c<64} x[b,c,neigh[n,k]] * W[o,k*64+c] + bias[o]
// B=4, N_VERTS=40962, K_RING=19, C=64. Storage: x,W,b,out fp32 (values
// bf16-representable), neigh int32. bf16 MFMA path near-exact (1.6e-2).
//
// R10: single-wave workgroups -> NO barriers, NO LDS; wave = 64 verts x 64
// outs. W frags straight from global (L2-hot; addressing verified in R7).
// amdgpu_waves_per_eu(2,2) pins 2 waves/SIMD -> ~256 VGPR budget so the
// depth-2 gather + depth-4 neigh prefetch stays in registers (R7/R9 failed
// because the occupancy-chasing allocator collapsed the pipeline to 64 regs).

#define NV   40962
#define KR   19
#define CIN  64
#define COUT 64
#define NB   4
#define NCHUNK 641   // ceil(NV/64)

typedef __bf16 bf16;
typedef __bf16 bf16x8 __attribute__((ext_vector_type(8)));
typedef float  floatx4 __attribute__((ext_vector_type(4)));

#define XT_ELEMS ((size_t)NB * NV * CIN)
#define WB_OFF   ((XT_ELEMS * 2 + 255) & ~(size_t)255)
#define WS_NEED  (WB_OFF + (size_t)COUT * KR * CIN * 2)

// ---------------------------------------------------------------------------
// Kernel 1: x (B,C,N) fp32 -> xt (B,N,64) bf16 (row per vertex = 128B line).
// ---------------------------------------------------------------------------
__global__ __launch_bounds__(256) void transpose_kernel(
    const float* __restrict__ x, bf16* __restrict__ xt)
{
    __shared__ float tile[64 * 65];
    const int b  = blockIdx.y;
    const int v0 = blockIdx.x * 64;
    const int t  = threadIdx.x;

    const int vl = t & 63;
    const int c0 = t >> 6;
    const int vg = min(v0 + vl, NV - 1);
    #pragma unroll
    for (int p = 0; p < 16; ++p) {
        int c = c0 * 16 + p;
        tile[vl * 65 + c] = x[((size_t)(b * CIN + c)) * NV + vg];
    }
    __syncthreads();

    const int v = t >> 2;
    const int q = t & 3;
    if (v0 + v < NV) {
        #pragma unroll
        for (int p = 0; p < 2; ++p) {
            int chunk = q + p * 4;
            bf16x8 o;
            #pragma unroll
            for (int j = 0; j < 8; ++j)
                o[j] = (bf16)tile[v * 65 + chunk * 8 + j];
            *(bf16x8*)&xt[((size_t)(b * NV + v0 + v)) * 64 + chunk * 8] = o;
        }
    }
}

// ---------------------------------------------------------------------------
// Kernel 1b: W fp32 (64x1216) -> bf16 (152 KB, once)
// ---------------------------------------------------------------------------
__global__ __launch_bounds__(256) void convw_kernel(
    const float* __restrict__ W, bf16* __restrict__ Wb)
{
    int i = blockIdx.x * 256 + threadIdx.x;
    const int total4 = COUT * KR * CIN / 4;
    if (i < total4) {
        float4 v = ((const float4*)W)[i];
        bf16* p = Wb + (size_t)i * 4;
        p[0] = (bf16)v.x; p[1] = (bf16)v.y; p[2] = (bf16)v.z; p[3] = (bf16)v.w;
    }
}

// ---------------------------------------------------------------------------
// Kernel 2: barrier-free single-wave gather-GEMM, mfma_f32_16x16x32_bf16.
//   A = W (m=o): lane holds W[ot*16+l15][r*64+kc*32+g*8 ..+7]  (16B contig)
//   B = gathered x (n=vertex): xt row halves at g*8 / 32+g*8
//   D: col(lane&15)=vertex, row((lane>>4)*4+reg)=o
// Pipelines: neigh depth 4 (vv[r&3]), gather depth 2 (xf[r&1]), W at-use
// (L2-hot, hoistable by scheduler under the 256-reg budget).
// XCD swizzle: batch = (blockIdx&7)>>1 pins each batch to one XCD pair.
// ---------------------------------------------------------------------------
__global__ __launch_bounds__(64)
__attribute__((amdgpu_waves_per_eu(2, 2)))
void conv_kernel(
    const int*   __restrict__ neigh,
    const bf16*  __restrict__ xt,
    const bf16*  __restrict__ Wb,     // (64, 1216) bf16
    const float* __restrict__ bias,   // (64,) fp32
    float*       __restrict__ out)    // (B, 64, NV) fp32
{
    const int i     = blockIdx.x;
    const int b     = (i & 7) >> 1;
    const int chunk = (i >> 3) * 2 + (i & 1);
    if (chunk >= NCHUNK) return;
    const int n0    = chunk * 64;

    const int lane = threadIdx.x;     // 0..63 (single wave)
    const int l15  = lane & 15;
    const int g    = lane >> 4;

    int nn[4], ib[4];
    #pragma unroll
    for (int s = 0; s < 4; ++s) {
        nn[s] = n0 + s * 16 + l15;
        ib[s] = min(nn[s], NV - 1) * KR;
    }

    const bf16* xb = xt + (((size_t)b * NV) << 6) + g * 8;   // + (v<<6)
    const bf16* wp = Wb + (size_t)l15 * (KR * 64) + g * 8;   // + ot*16*1216

    floatx4 acc[4][4];
    #pragma unroll
    for (int s = 0; s < 4; ++s)
        #pragma unroll
        for (int o = 0; o < 4; ++o)
            acc[s][o] = (floatx4){0.f, 0.f, 0.f, 0.f};

    // ---- neigh pipeline: vv[r&3][s] = ring r's (clamped) vertex id
    int vv[4][4];
    #pragma unroll
    for (int r = 0; r < 4; ++r) {
        #pragma unroll
        for (int s = 0; s < 4; ++s) {
            int v = neigh[ib[s] + r];
            vv[r][s] = ((unsigned)v < (unsigned)NV) ? v : 0;
        }
    }

    // ---- gather pipeline: xf[r&1][s][half] holds ring r's x-frags
    bf16x8 xf[2][4][2];
    #pragma unroll
    for (int r = 0; r < 2; ++r) {
        #pragma unroll
        for (int s = 0; s < 4; ++s) {
            const bf16* p = xb + ((size_t)vv[r][s] << 6);
            xf[r][s][0] = *(const bf16x8*)(p);
            xf[r][s][1] = *(const bf16x8*)(p + 32);
        }
    }

    #pragma unroll
    for (int r = 0; r < KR; ++r) {
        // W frags for ring r (global; L2-hot; scheduler hoists under budget)
        bf16x8 wf[4][2];
        #pragma unroll
        for (int ot = 0; ot < 4; ++ot)
            #pragma unroll
            for (int kc = 0; kc < 2; ++kc)
                wf[ot][kc] = *(const bf16x8*)
                    (wp + (size_t)(ot * 16) * (KR * 64) + r * 64 + kc * 32);

        // 32 MFMAs: each W frag reused across 4 vertex subtiles
        #pragma unroll
        for (int ot = 0; ot < 4; ++ot)
            #pragma unroll
            for (int kc = 0; kc < 2; ++kc)
                #pragma unroll
                for (int s = 0; s < 4; ++s)
                    acc[s][ot] = __builtin_amdgcn_mfma_f32_16x16x32_bf16(
                        wf[ot][kc], xf[r & 1][s][kc], acc[s][ot], 0, 0, 0);

        // neigh prefetch ring r+4 into slot r&3 (ring r's id is dead)
        if (r + 4 < KR) {
            #pragma unroll
            for (int s = 0; s < 4; ++s) {
                int v = neigh[ib[s] + r + 4];
                vv[r & 3][s] = ((unsigned)v < (unsigned)NV) ? v : 0;
            }
        }
        // gather ring r+2 into the stage just consumed (vv slot (r+2)&3)
        if (r + 2 < KR) {
            #pragma unroll
            for (int s = 0; s < 4; ++s) {
                const bf16* p = xb + ((size_t)vv[(r + 2) & 3][s] << 6);
                xf[r & 1][s][0] = *(const bf16x8*)(p);
                xf[r & 1][s][1] = *(const bf16x8*)(p + 32);
            }
        }
    }

    #pragma unroll
    for (int ot = 0; ot < 4; ++ot) {
        #pragma unroll
        for (int ii = 0; ii < 4; ++ii) {
            int o = ot * 16 + g * 4 + ii;
            float bv = bias[o];
            #pragma unroll
            for (int s = 0; s < 4; ++s) {
                if (nn[s] < NV) {
                    out[((size_t)(b * COUT + o)) * NV + nn[s]] =
                        acc[s][ot][ii] + bv;
                }
            }
        }
    }
}

// ---------------------------------------------------------------------------
// Fallback (no workspace): one block per (b,n); fp32 in/out.
// ---------------------------------------------------------------------------
__global__ __launch_bounds__(64) void fallback_kernel(
    const int*   __restrict__ neigh,
    const float* __restrict__ x,
    const float* __restrict__ W,
    const float* __restrict__ bias,
    float*       __restrict__ out)
{
    __shared__ float xg[KR * CIN];
    const int bn = blockIdx.x;
    const int b  = bn / NV;
    const int n  = bn % NV;
    const int t  = threadIdx.x;

    for (int k = t; k < KR * CIN; k += 64) {
        int r = k / CIN, c = k - r * CIN;
        int v = neigh[n * KR + r];
        v = ((unsigned)v < (unsigned)NV) ? v : 0;
        xg[k] = x[((size_t)(b * CIN + c)) * NV + v];
    }
    __syncthreads();

    float s = bias[t];
    const float* wrow = W + (size_t)t * (KR * CIN);
    for (int k = 0; k < KR * CIN; ++k) s += xg[k] * wrow[k];
    out[((size_t)(b * COUT + t)) * NV + n] = s;
}

// ---------------------------------------------------------------------------
extern "C" void kernel_launch(void* const* d_in, const int* in_sizes, int n_in,
                              void* d_out, int out_size, void* d_ws, size_t ws_size,
                              hipStream_t stream)
{
    const float* x     = (const float*)d_in[0];
    const int*   neigh = (const int*)d_in[1];
    const float* W     = (const float*)d_in[2];
    const float* bias  = (const float*)d_in[3];
    float* out = (float*)d_out;

    if (d_ws != nullptr && ws_size >= WS_NEED) {
        bf16* xt = (bf16*)d_ws;
        bf16* Wb = (bf16*)((char*)d_ws + WB_OFF);

        dim3 tgrid((NV + 63) / 64, NB);
        transpose_kernel<<<tgrid, 256, 0, stream>>>(x, xt);
        convw_kernel<<<(COUT * KR * CIN / 4 + 255) / 256, 256, 0, stream>>>(W, Wb);

        // single-wave blocks: (i&7)>>1 = batch (XCD pair), rest = 64-vert chunk
        int nblk = 8 * ((NCHUNK + 1) / 2);          // 2568
        conv_kernel<<<nblk, 64, 0, stream>>>(neigh, xt, Wb, bias, out);
    } else {
        fallback_kernel<<<NB * NV, 64, 0, stream>>>(neigh, x, W, bias, out);
    }
}